// Round 7
// baseline (227.110 us; speedup 1.0000x reference)
//
#include <hip/hip_runtime.h>
#include <stdint.h>

// Problem constants (B,S,D,O,E) = (16,512,512,512,8)
#define B_ 16
#define S_ 512
#define D_ 512
#define O_ 512
#define E_ 8

typedef unsigned short ushort_t;
typedef __attribute__((ext_vector_type(8))) short short8;
typedef __attribute__((ext_vector_type(8))) unsigned short ushort8;
typedef __attribute__((ext_vector_type(4))) unsigned short ushort4_t;
typedef __attribute__((ext_vector_type(4))) float f32x4;
typedef __attribute__((ext_vector_type(4))) unsigned int u32x4;

// round-to-nearest-even f32 -> bf16 (scalar)
__device__ __forceinline__ ushort_t f2bf(float f) {
  union { float f; unsigned int u; } v; v.f = f;
  unsigned int u = v.u;
  return (ushort_t)((u + 0x7fffu + ((u >> 16) & 1u)) >> 16);
}

// packed 2x f32 -> 2x bf16 (RNE), single instruction
__device__ __forceinline__ unsigned int cvtpk(float lo, float hi) {
  unsigned int r;
  asm("v_cvt_pk_bf16_f32 %0, %1, %2" : "=v"(r) : "v"(lo), "v"(hi));
  return r;
}

// async global->LDS, 16B per lane (wave-uniform LDS base + lane*16 pattern)
__device__ __forceinline__ void gld_lds16(const void* g, void* l) {
  __builtin_amdgcn_global_load_lds((__attribute__((address_space(1))) void*)(g),
                                   (__attribute__((address_space(3))) void*)(l),
                                   16, 0, 0);
}

// ---------------- prep kernels ----------------

// Fused: gates (B,E,S) = sigmoid(x.Wg[e]+bg[e])  AND  xb = bf16(x).
__global__ __launch_bounds__(256) void k_prep(const float* __restrict__ x,
                                              const float* __restrict__ Wg,
                                              const float* __restrict__ bg,
                                              float* __restrict__ gates,
                                              ushort_t* __restrict__ xb) {
  const int wave = threadIdx.x >> 6, lane = threadIdx.x & 63;
  const int row = blockIdx.x * 4 + wave;  // b*S + s
  const float4* xr = (const float4*)(x + (size_t)row * D_);
  float4 x0 = xr[lane], x1 = xr[lane + 64];

  ushort4_t u0, u1;
  u0[0] = f2bf(x0.x); u0[1] = f2bf(x0.y); u0[2] = f2bf(x0.z); u0[3] = f2bf(x0.w);
  u1[0] = f2bf(x1.x); u1[1] = f2bf(x1.y); u1[2] = f2bf(x1.z); u1[3] = f2bf(x1.w);
  *(ushort4_t*)(xb + (size_t)row * D_ + 4 * lane) = u0;
  *(ushort4_t*)(xb + (size_t)row * D_ + 256 + 4 * lane) = u1;

  float p[E_];
#pragma unroll
  for (int e = 0; e < E_; ++e) {
    const float4* wr_ = (const float4*)(Wg + e * D_);
    float4 w0 = wr_[lane], w1 = wr_[lane + 64];
    p[e] = x0.x * w0.x + x0.y * w0.y + x0.z * w0.z + x0.w * w0.w +
           x1.x * w1.x + x1.y * w1.y + x1.z * w1.z + x1.w * w1.w;
  }
#pragma unroll
  for (int e = 0; e < E_; ++e) {
    float v = p[e];
#pragma unroll
    for (int off = 32; off > 0; off >>= 1) v += __shfl_xor(v, off, 64);
    p[e] = v;
  }
  const int b = row >> 9, s = row & (S_ - 1);
#pragma unroll
  for (int e = 0; e < E_; ++e)
    if (lane == e) {
      float z = p[e] + bg[e];
      gates[((size_t)(b * E_ + e)) * S_ + s] = 1.f / (1.f + __expf(-z));
    }
}

// Wc (E,D,O) f32 -> WcT (E,O,D) bf16 via LDS tile transpose (64x64 tiles)
__global__ __launch_bounds__(256) void k_wcT(const float* __restrict__ Wc,
                                             ushort_t* __restrict__ WcT) {
  __shared__ float tile[64][65];
  const int e = blockIdx.z, d0 = blockIdx.y * 64, o0 = blockIdx.x * 64;
  const float* src = Wc + (size_t)e * D_ * O_;
#pragma unroll
  for (int i = 0; i < 16; ++i) {
    int idx = i * 256 + threadIdx.x;
    int r = idx >> 6, c = idx & 63;
    tile[r][c] = src[(size_t)(d0 + r) * O_ + o0 + c];
  }
  __syncthreads();
  ushort_t* dst = WcT + (size_t)e * O_ * D_;
#pragma unroll
  for (int i = 0; i < 16; ++i) {
    int idx = i * 256 + threadIdx.x;
    int r = idx >> 6, c = idx & 63;  // r: o-row, c: d-col
    dst[(size_t)(o0 + r) * D_ + d0 + c] = f2bf(tile[c][r]);
  }
}

// ---------------- GEMM1 (m97 structure, unchanged) ----------------

__global__ __launch_bounds__(256) void k_gemm1g(const ushort_t* __restrict__ WcT,
                                                const ushort_t* __restrict__ xb,
                                                const float* __restrict__ bc,
                                                const float* __restrict__ gates,
                                                ushort_t* __restrict__ hTg) {
  __shared__ __attribute__((aligned(16))) ushort_t lA[128 * 64];
  __shared__ __attribute__((aligned(16))) ushort_t lB[128 * 64];
  const int tid = threadIdx.x;
  const int m0 = blockIdx.x * 128, n0 = blockIdx.y * 128;
  const int tr = tid >> 3, tc = (tid & 7) * 8;
  const int lane = tid & 63, wid = tid >> 6;
  const int wr = wid >> 1, wc = wid & 1;
  const int lr = lane & 15, lk = (lane >> 4) * 8, lq = lane >> 4;

  f32x4 acc[4][4];
#pragma unroll
  for (int i = 0; i < 4; ++i)
#pragma unroll
    for (int j = 0; j < 4; ++j) acc[i][j] = (f32x4){0.f, 0.f, 0.f, 0.f};

  const ushort_t* gA = WcT + (size_t)(m0 + tr) * D_ + tc;
  const ushort_t* gB = xb + (size_t)(n0 + tr) * D_ + tc;

  for (int kk = 0; kk < 8; ++kk) {
    const int k0 = kk * 64;
    __syncthreads();
#pragma unroll
    for (int i = 0; i < 4; ++i) {
      gld_lds16(gA + (size_t)(32 * i) * D_ + k0, lA + tid * 8 + i * 2048);
      gld_lds16(gB + (size_t)(32 * i) * D_ + k0, lB + tid * 8 + i * 2048);
    }
    asm volatile("s_waitcnt vmcnt(0)" ::: "memory");
    __syncthreads();
    const ushort_t* pA = lA + (wr * 64 + lr) * 64 + lk;
    const ushort_t* pB = lB + (wc * 64 + lr) * 64 + lk;
#pragma unroll
    for (int ks = 0; ks < 2; ++ks) {
      short8 av[4], bv[4];
#pragma unroll
      for (int mi = 0; mi < 4; ++mi) av[mi] = *(const short8*)(pA + mi * 16 * 64 + ks * 32);
#pragma unroll
      for (int ni = 0; ni < 4; ++ni) bv[ni] = *(const short8*)(pB + ni * 16 * 64 + ks * 32);
#pragma unroll
      for (int mi = 0; mi < 4; ++mi)
#pragma unroll
        for (int ni = 0; ni < 4; ++ni)
          acc[mi][ni] = __builtin_amdgcn_mfma_f32_16x16x32_bf16(av[mi], bv[ni], acc[mi][ni], 0, 0, 0);
    }
  }

#pragma unroll
  for (int mi = 0; mi < 4; ++mi) {
    const int m_g = m0 + wr * 64 + mi * 16 + lq * 4;
    const int e = m_g >> 9;
#pragma unroll
    for (int ni = 0; ni < 4; ++ni) {
      const int n_g = n0 + wc * 64 + ni * 16 + lr;
      const int b = n_g >> 9, s = n_g & (S_ - 1);
      const float g = gates[((size_t)(b * E_ + e)) * S_ + s];
      f32x4 v = acc[mi][ni];
#pragma unroll
      for (int r = 0; r < 4; ++r)
        hTg[(size_t)(m_g + r) * (B_ * S_) + n_g] = f2bf((v[r] + bc[m_g + r]) * g);
    }
  }
}

// ---------------- GEMM2: deep pipeline (A 2-deep regs, B early-issue dbuf) -------

// load one 128x64 f32 adj tile into the given pf set (plain loads; compiler tracks)
#define LOAD_PFA(Q0, Q1, Q2, Q3, Q4, Q5, Q6, Q7, KIDX)                               \
  {                                                                                  \
    const int e_ = sp * EPB + ((KIDX) >> 3), t_ = ((KIDX) & 7) * 64;                 \
    const float* g_ = adj + ((size_t)((b * E_ + e_) * S_ + s0 + tr)) * S_ + t_ + tcf;\
    Q0 = *(const float4*)(g_);            Q1 = *(const float4*)(g_ + 4);             \
    Q2 = *(const float4*)(g_ + 32 * S_);  Q3 = *(const float4*)(g_ + 32 * S_ + 4);   \
    Q4 = *(const float4*)(g_ + 64 * S_);  Q5 = *(const float4*)(g_ + 64 * S_ + 4);   \
    Q6 = *(const float4*)(g_ + 96 * S_);  Q7 = *(const float4*)(g_ + 96 * S_ + 4);   \
  }

// issue 4 gld_lds of one 128x64 bf16 hTg tile into lB[BUF] (source pre-swizzled)
#define ISSUE_B(BUF, KIDX)                                                           \
  {                                                                                  \
    const int e_ = sp * EPB + ((KIDX) >> 3), t_ = ((KIDX) & 7) * 64;                 \
    const ushort_t* g_ = hTg + ((size_t)(e_ * O_ + o0 + tr)) * (B_ * S_) +           \
                         b * S_ + t_ + chS * 8;                                      \
    gld_lds16(g_ + (size_t)0 * (B_ * S_),  &lB[BUF][tid * 8 + 0 * 2048]);            \
    gld_lds16(g_ + (size_t)32 * (B_ * S_), &lB[BUF][tid * 8 + 1 * 2048]);            \
    gld_lds16(g_ + (size_t)64 * (B_ * S_), &lB[BUF][tid * 8 + 2 * 2048]);            \
    gld_lds16(g_ + (size_t)96 * (B_ * S_), &lB[BUF][tid * 8 + 3 * 2048]);            \
  }

// One K-subtile. Order: bar1 / issue B(KK+1) / cvt pf(KK)->lA (compiler auto-wait)
// / reload same pf set with A(KK+2) / counted vmcnt+lgkm / bar2 / MFMA.
// Steady-state wait leaves A(KK+1)+B(KK+1)+A(KK+2) = 20 ops in flight.
#define SUBITER(KK, Q0, Q1, Q2, Q3, Q4, Q5, Q6, Q7, RBUF, DOB, DOA, VM)              \
  {                                                                                  \
    __builtin_amdgcn_s_barrier();                                                    \
    __builtin_amdgcn_sched_barrier(0);                                               \
    if (DOB) ISSUE_B((RBUF) ^ 1, (KK) + 1);                                          \
    { /* cvt pf (tile KK) -> lA, swizzled chunk */                                   \
      u32x4 w_;                                                                      \
      w_[0] = cvtpk(Q0.x, Q0.y); w_[1] = cvtpk(Q0.z, Q0.w);                          \
      w_[2] = cvtpk(Q1.x, Q1.y); w_[3] = cvtpk(Q1.z, Q1.w);                          \
      *(u32x4*)(lA + 0 * 2048 + wrA) = w_;                                           \
      w_[0] = cvtpk(Q2.x, Q2.y); w_[1] = cvtpk(Q2.z, Q2.w);                          \
      w_[2] = cvtpk(Q3.x, Q3.y); w_[3] = cvtpk(Q3.z, Q3.w);                          \
      *(u32x4*)(lA + 1 * 2048 + wrA) = w_;                                           \
      w_[0] = cvtpk(Q4.x, Q4.y); w_[1] = cvtpk(Q4.z, Q4.w);                          \
      w_[2] = cvtpk(Q5.x, Q5.y); w_[3] = cvtpk(Q5.z, Q5.w);                          \
      *(u32x4*)(lA + 2 * 2048 + wrA) = w_;                                           \
      w_[0] = cvtpk(Q6.x, Q6.y); w_[1] = cvtpk(Q6.z, Q6.w);                          \
      w_[2] = cvtpk(Q7.x, Q7.y); w_[3] = cvtpk(Q7.z, Q7.w);                          \
      *(u32x4*)(lA + 3 * 2048 + wrA) = w_;                                           \
    }                                                                                \
    if (DOA) LOAD_PFA(Q0, Q1, Q2, Q3, Q4, Q5, Q6, Q7, (KK) + 2);                     \
    asm volatile("s_waitcnt vmcnt(" #VM ") lgkmcnt(0)" ::: "memory");                \
    __builtin_amdgcn_sched_barrier(0);                                               \
    __builtin_amdgcn_s_barrier();                                                    \
    __builtin_amdgcn_sched_barrier(0);                                               \
    {                                                                                \
      const ushort_t* pA_ = lA + (wr * 64 + lr) * 64;                                \
      const ushort_t* pB_ = &lB[RBUF][(wc * 64 + lr) * 64];                          \
      __builtin_amdgcn_s_setprio(1);                                                 \
      _Pragma("unroll")                                                              \
      for (int ks = 0; ks < 2; ++ks) {                                               \
        const int co_ = ks ? cks1 : cks0;                                            \
        short8 av[4], bv[4];                                                         \
        _Pragma("unroll")                                                            \
        for (int mi = 0; mi < 4; ++mi) av[mi] = *(const short8*)(pA_ + mi * 1024 + co_);\
        _Pragma("unroll")                                                            \
        for (int ni = 0; ni < 4; ++ni) bv[ni] = *(const short8*)(pB_ + ni * 1024 + co_);\
        _Pragma("unroll")                                                            \
        for (int mi = 0; mi < 4; ++mi)                                               \
          _Pragma("unroll")                                                          \
          for (int ni = 0; ni < 4; ++ni)                                             \
            acc[mi][ni] = __builtin_amdgcn_mfma_f32_16x16x32_bf16(av[mi], bv[ni],    \
                                                                  acc[mi][ni], 0, 0, 0);\
      }                                                                              \
      __builtin_amdgcn_s_setprio(0);                                                 \
    }                                                                                \
  }

template <int SPLIT>
__global__ __launch_bounds__(256, 3) void k_gemm2f(const float* __restrict__ adj,
                                                   const ushort_t* __restrict__ hTg,
                                                   float* __restrict__ dst) {
  __shared__ __attribute__((aligned(16))) ushort_t lA[128 * 64];      // s x t
  __shared__ __attribute__((aligned(16))) ushort_t lB[2][128 * 64];   // o x t, dbuf
  const int tid = threadIdx.x;
  const int w = blockIdx.x;
  const int xcd = w & 7;
  const int r_ = w >> 3;
  const int xo = r_ & 3;          // o-tile
  const int yo = (r_ >> 2) & 3;   // s-tile
  const int zhi = r_ >> 4;        // z / 8
  const int z = xcd + 8 * zhi;    // 0..B_*SPLIT-1
  const int b = z / SPLIT, sp = z % SPLIT;
  const int o0 = xo * 128, s0 = yo * 128;
  constexpr int EPB = E_ / SPLIT;
  constexpr int NKK = EPB * 8;
  const int tr = tid >> 3;                      // staging row within 32-block
  const int tcf = (tid & 7) * 8;                // nominal col (elements)
  const int chS = (tid & 7) ^ (tr & 7);         // swizzled 16B chunk
  const int wrA = tr * 64 + chS * 8;            // lA write offset (elements)
  const int lane = tid & 63, wid = tid >> 6;
  const int wr = wid >> 1, wc = wid & 1;
  const int lr = lane & 15, lq = lane >> 4;
  const int rsw = lane & 7;                     // row&7 for fragment rows
  const int cks0 = (((lane >> 4) + 0) ^ rsw) * 8;
  const int cks1 = (((lane >> 4) + 4) ^ rsw) * 8;

  f32x4 acc[4][4];
#pragma unroll
  for (int i = 0; i < 4; ++i)
#pragma unroll
    for (int j = 0; j < 4; ++j) acc[i][j] = (f32x4){0.f, 0.f, 0.f, 0.f};

  // two adj prefetch reg sets (even/odd kk), compiler-tracked
  float4 pe0, pe1, pe2, pe3, pe4, pe5, pe6, pe7;
  float4 po0, po1, po2, po3, po4, po5, po6, po7;

  // prologue (order matters for uniform vmcnt counts): A(0), B(0), A(1)
  LOAD_PFA(pe0, pe1, pe2, pe3, pe4, pe5, pe6, pe7, 0);
  ISSUE_B(0, 0);
  LOAD_PFA(po0, po1, po2, po3, po4, po5, po6, po7, 1);

#pragma unroll 1
  for (int kk = 0; kk <= NKK - 4; kk += 2) {
    SUBITER(kk,     pe0, pe1, pe2, pe3, pe4, pe5, pe6, pe7, 0, 1, 1, 20)
    SUBITER(kk + 1, po0, po1, po2, po3, po4, po5, po6, po7, 1, 1, 1, 20)
  }
  SUBITER(NKK - 2, pe0, pe1, pe2, pe3, pe4, pe5, pe6, pe7, 0, 1, 0, 12)
  SUBITER(NKK - 1, po0, po1, po2, po3, po4, po5, po6, po7, 1, 0, 0, 0)

  float* base = dst + ((size_t)sp * B_ + b) * S_ * O_;
#pragma unroll
  for (int mi = 0; mi < 4; ++mi) {
    const int s_g = s0 + wr * 64 + mi * 16 + lq * 4;
#pragma unroll
    for (int ni = 0; ni < 4; ++ni) {
      const int o_g = o0 + wc * 64 + ni * 16 + lr;
      f32x4 v = acc[mi][ni];
#pragma unroll
      for (int r = 0; r < 4; ++r) {
        float val = v[r];
        if (SPLIT == 1) val = fmaxf(val, 0.f);
        base[(size_t)(s_g + r) * O_ + o_g] = val;
      }
    }
  }
}

// reduce SPLIT partials + relu -> out (B,S,O) f32
template <int SPLIT>
__global__ __launch_bounds__(256) void k_reduce(const float* __restrict__ part,
                                                float* __restrict__ out) {
  constexpr size_t N = (size_t)B_ * S_ * O_;
  size_t i4 = ((size_t)blockIdx.x * 256 + threadIdx.x) * 4;
  f32x4 a = *(const f32x4*)(part + i4);
#pragma unroll
  for (int s = 1; s < SPLIT; ++s) {
    f32x4 p = *(const f32x4*)(part + (size_t)s * N + i4);
    a[0] += p[0]; a[1] += p[1]; a[2] += p[2]; a[3] += p[3];
  }
  f32x4 o;
  o[0] = fmaxf(a[0], 0.f); o[1] = fmaxf(a[1], 0.f);
  o[2] = fmaxf(a[2], 0.f); o[3] = fmaxf(a[3], 0.f);
  *(f32x4*)(out + i4) = o;
}

// ---------------- launch ----------------

extern "C" void kernel_launch(void* const* d_in, const int* in_sizes, int n_in,
                              void* d_out, int out_size, void* d_ws, size_t ws_size,
                              hipStream_t stream) {
  const float* x   = (const float*)d_in[0];  // (B,S,D)
  const float* adj = (const float*)d_in[1];  // (B,E,S,S)
  const float* Wg  = (const float*)d_in[2];  // (E,D)
  const float* bg  = (const float*)d_in[3];  // (E,)
  const float* Wc  = (const float*)d_in[4];  // (E,D,O)
  const float* bc  = (const float*)d_in[5];  // (E,O)
  float* out = (float*)d_out;                // (B,S,O)

  // workspace carve (all 16B-aligned)
  char* ws = (char*)d_ws;
  float* gates  = (float*)ws;    ws += (size_t)B_ * E_ * S_ * 4;        //  0.26 MB
  ushort_t* xb  = (ushort_t*)ws; ws += (size_t)B_ * S_ * D_ * 2;        //  8.4  MB
  ushort_t* WcT = (ushort_t*)ws; ws += (size_t)E_ * O_ * D_ * 2;        //  4.2  MB
  ushort_t* hTg = (ushort_t*)ws; ws += (size_t)E_ * O_ * B_ * S_ * 2;   // 67.1  MB
  float* part   = (float*)ws;                                           // SPLIT*16.8 MB
  const size_t base_bytes = (size_t)((char*)part - (char*)d_ws);
  const size_t part_sz = (size_t)B_ * S_ * O_ * sizeof(float);

  int split = 1;
  if (ws_size >= base_bytes + 4 * part_sz) split = 4;
  else if (ws_size >= base_bytes + 2 * part_sz) split = 2;

  k_prep<<<dim3((B_ * S_) / 4), dim3(256), 0, stream>>>(x, Wg, bg, gates, xb);
  k_wcT<<<dim3(O_ / 64, D_ / 64, E_), dim3(256), 0, stream>>>(Wc, WcT);
  k_gemm1g<<<dim3((E_ * O_) / 128, (B_ * S_) / 128), dim3(256), 0, stream>>>(WcT, xb, bc, gates, hTg);

  const int red_blocks = (int)(((size_t)B_ * S_ * O_) / (256 * 4));
  if (split == 4) {
    k_gemm2f<4><<<dim3(16 * B_ * 4), dim3(256), 0, stream>>>(adj, hTg, part);
    k_reduce<4><<<dim3(red_blocks), dim3(256), 0, stream>>>(part, out);
  } else if (split == 2) {
    k_gemm2f<2><<<dim3(16 * B_ * 2), dim3(256), 0, stream>>>(adj, hTg, part);
    k_reduce<2><<<dim3(red_blocks), dim3(256), 0, stream>>>(part, out);
  } else {
    k_gemm2f<1><<<dim3(16 * B_), dim3(256), 0, stream>>>(adj, hTg, out);
  }
}

// Round 8
// 146.671 us; speedup vs baseline: 1.5484x; 1.5484x over previous
//
#include <hip/hip_runtime.h>
#include <stdint.h>

// Problem constants (B,S,D,O,E) = (16,512,512,512,8)
#define B_ 16
#define S_ 512
#define D_ 512
#define O_ 512
#define E_ 8

typedef unsigned short ushort_t;
typedef __attribute__((ext_vector_type(8))) short short8;
typedef __attribute__((ext_vector_type(8))) unsigned short ushort8;
typedef __attribute__((ext_vector_type(4))) unsigned short ushort4_t;
typedef __attribute__((ext_vector_type(4))) float f32x4;
typedef __attribute__((ext_vector_type(4))) unsigned int u32x4;

// round-to-nearest-even f32 -> bf16 (scalar)
__device__ __forceinline__ ushort_t f2bf(float f) {
  union { float f; unsigned int u; } v; v.f = f;
  unsigned int u = v.u;
  return (ushort_t)((u + 0x7fffu + ((u >> 16) & 1u)) >> 16);
}

// bf16 (as ushort) -> f32
__device__ __forceinline__ float bf2f(ushort_t h) {
  union { unsigned int u; float f; } v; v.u = ((unsigned int)h) << 16;
  return v.f;
}

// packed 2x f32 -> 2x bf16 (RNE), single instruction
__device__ __forceinline__ unsigned int cvtpk(float lo, float hi) {
  unsigned int r;
  asm("v_cvt_pk_bf16_f32 %0, %1, %2" : "=v"(r) : "v"(lo), "v"(hi));
  return r;
}

// async global->LDS, 16B per lane (wave-uniform LDS base + lane*16 pattern)
__device__ __forceinline__ void gld_lds16(const void* g, void* l) {
  __builtin_amdgcn_global_load_lds((__attribute__((address_space(1))) void*)(g),
                                   (__attribute__((address_space(3))) void*)(l),
                                   16, 0, 0);
}

// ---------------- prep kernels ----------------

// Fused: gates (B,E,S) = sigmoid(x.Wg[e]+bg[e])  AND  xb = bf16(x).
__global__ __launch_bounds__(256) void k_prep(const float* __restrict__ x,
                                              const float* __restrict__ Wg,
                                              const float* __restrict__ bg,
                                              float* __restrict__ gates,
                                              ushort_t* __restrict__ xb) {
  const int wave = threadIdx.x >> 6, lane = threadIdx.x & 63;
  const int row = blockIdx.x * 4 + wave;  // b*S + s
  const float4* xr = (const float4*)(x + (size_t)row * D_);
  float4 x0 = xr[lane], x1 = xr[lane + 64];

  ushort4_t u0, u1;
  u0[0] = f2bf(x0.x); u0[1] = f2bf(x0.y); u0[2] = f2bf(x0.z); u0[3] = f2bf(x0.w);
  u1[0] = f2bf(x1.x); u1[1] = f2bf(x1.y); u1[2] = f2bf(x1.z); u1[3] = f2bf(x1.w);
  *(ushort4_t*)(xb + (size_t)row * D_ + 4 * lane) = u0;
  *(ushort4_t*)(xb + (size_t)row * D_ + 256 + 4 * lane) = u1;

  float p[E_];
#pragma unroll
  for (int e = 0; e < E_; ++e) {
    const float4* wr_ = (const float4*)(Wg + e * D_);
    float4 w0 = wr_[lane], w1 = wr_[lane + 64];
    p[e] = x0.x * w0.x + x0.y * w0.y + x0.z * w0.z + x0.w * w0.w +
           x1.x * w1.x + x1.y * w1.y + x1.z * w1.z + x1.w * w1.w;
  }
#pragma unroll
  for (int e = 0; e < E_; ++e) {
    float v = p[e];
#pragma unroll
    for (int off = 32; off > 0; off >>= 1) v += __shfl_xor(v, off, 64);
    p[e] = v;
  }
  const int b = row >> 9, s = row & (S_ - 1);
#pragma unroll
  for (int e = 0; e < E_; ++e)
    if (lane == e) {
      float z = p[e] + bg[e];
      gates[((size_t)(b * E_ + e)) * S_ + s] = 1.f / (1.f + __expf(-z));
    }
}

// Wc (E,D,O) f32 -> WcT (E,O,D) bf16 via LDS tile transpose (64x64 tiles)
__global__ __launch_bounds__(256) void k_wcT(const float* __restrict__ Wc,
                                             ushort_t* __restrict__ WcT) {
  __shared__ float tile[64][65];
  const int e = blockIdx.z, d0 = blockIdx.y * 64, o0 = blockIdx.x * 64;
  const float* src = Wc + (size_t)e * D_ * O_;
#pragma unroll
  for (int i = 0; i < 16; ++i) {
    int idx = i * 256 + threadIdx.x;
    int r = idx >> 6, c = idx & 63;
    tile[r][c] = src[(size_t)(d0 + r) * O_ + o0 + c];
  }
  __syncthreads();
  ushort_t* dst = WcT + (size_t)e * O_ * D_;
#pragma unroll
  for (int i = 0; i < 16; ++i) {
    int idx = i * 256 + threadIdx.x;
    int r = idx >> 6, c = idx & 63;  // r: o-row, c: d-col
    dst[(size_t)(o0 + r) * D_ + d0 + c] = f2bf(tile[c][r]);
  }
}

// ---------------- GEMM1 (m97 structure, unchanged) ----------------

__global__ __launch_bounds__(256) void k_gemm1g(const ushort_t* __restrict__ WcT,
                                                const ushort_t* __restrict__ xb,
                                                const float* __restrict__ bc,
                                                const float* __restrict__ gates,
                                                ushort_t* __restrict__ hTg) {
  __shared__ __attribute__((aligned(16))) ushort_t lA[128 * 64];
  __shared__ __attribute__((aligned(16))) ushort_t lB[128 * 64];
  const int tid = threadIdx.x;
  const int m0 = blockIdx.x * 128, n0 = blockIdx.y * 128;
  const int tr = tid >> 3, tc = (tid & 7) * 8;
  const int lane = tid & 63, wid = tid >> 6;
  const int wr = wid >> 1, wc = wid & 1;
  const int lr = lane & 15, lk = (lane >> 4) * 8, lq = lane >> 4;

  f32x4 acc[4][4];
#pragma unroll
  for (int i = 0; i < 4; ++i)
#pragma unroll
    for (int j = 0; j < 4; ++j) acc[i][j] = (f32x4){0.f, 0.f, 0.f, 0.f};

  const ushort_t* gA = WcT + (size_t)(m0 + tr) * D_ + tc;
  const ushort_t* gB = xb + (size_t)(n0 + tr) * D_ + tc;

  for (int kk = 0; kk < 8; ++kk) {
    const int k0 = kk * 64;
    __syncthreads();
#pragma unroll
    for (int i = 0; i < 4; ++i) {
      gld_lds16(gA + (size_t)(32 * i) * D_ + k0, lA + tid * 8 + i * 2048);
      gld_lds16(gB + (size_t)(32 * i) * D_ + k0, lB + tid * 8 + i * 2048);
    }
    asm volatile("s_waitcnt vmcnt(0)" ::: "memory");
    __syncthreads();
    const ushort_t* pA = lA + (wr * 64 + lr) * 64 + lk;
    const ushort_t* pB = lB + (wc * 64 + lr) * 64 + lk;
#pragma unroll
    for (int ks = 0; ks < 2; ++ks) {
      short8 av[4], bv[4];
#pragma unroll
      for (int mi = 0; mi < 4; ++mi) av[mi] = *(const short8*)(pA + mi * 16 * 64 + ks * 32);
#pragma unroll
      for (int ni = 0; ni < 4; ++ni) bv[ni] = *(const short8*)(pB + ni * 16 * 64 + ks * 32);
#pragma unroll
      for (int mi = 0; mi < 4; ++mi)
#pragma unroll
        for (int ni = 0; ni < 4; ++ni)
          acc[mi][ni] = __builtin_amdgcn_mfma_f32_16x16x32_bf16(av[mi], bv[ni], acc[mi][ni], 0, 0, 0);
    }
  }

#pragma unroll
  for (int mi = 0; mi < 4; ++mi) {
    const int m_g = m0 + wr * 64 + mi * 16 + lq * 4;
    const int e = m_g >> 9;
#pragma unroll
    for (int ni = 0; ni < 4; ++ni) {
      const int n_g = n0 + wc * 64 + ni * 16 + lr;
      const int b = n_g >> 9, s = n_g & (S_ - 1);
      const float g = gates[((size_t)(b * E_ + e)) * S_ + s];
      f32x4 v = acc[mi][ni];
#pragma unroll
      for (int r = 0; r < 4; ++r)
        hTg[(size_t)(m_g + r) * (B_ * S_) + n_g] = f2bf((v[r] + bc[m_g + r]) * g);
    }
  }
}

// ---------------- GEMM2: round-6 pipeline + early-B + bf16 partials ------------

// load one 128x64 f32 adj tile into pf0..pf7 (plain C++ loads; compiler tracks)
#define LOAD_PFA(KIDX)                                                               \
  {                                                                                  \
    const int e_ = sp * EPB + ((KIDX) >> 3), t_ = ((KIDX) & 7) * 64;                 \
    const float* g_ = adj + ((size_t)((b * E_ + e_) * S_ + s0 + tr)) * S_ + t_ + tcf;\
    pf0 = *(const float4*)(g_);            pf1 = *(const float4*)(g_ + 4);           \
    pf2 = *(const float4*)(g_ + 32 * S_);  pf3 = *(const float4*)(g_ + 32 * S_ + 4); \
    pf4 = *(const float4*)(g_ + 64 * S_);  pf5 = *(const float4*)(g_ + 64 * S_ + 4); \
    pf6 = *(const float4*)(g_ + 96 * S_);  pf7 = *(const float4*)(g_ + 96 * S_ + 4); \
  }

// issue 4 gld_lds of one 128x64 bf16 hTg tile into lB[BUF] (source pre-swizzled)
#define ISSUE_B(BUF, KIDX)                                                           \
  {                                                                                  \
    const int e_ = sp * EPB + ((KIDX) >> 3), t_ = ((KIDX) & 7) * 64;                 \
    const ushort_t* g_ = hTg + ((size_t)(e_ * O_ + o0 + tr)) * (B_ * S_) +           \
                         b * S_ + t_ + chS * 8;                                      \
    gld_lds16(g_ + (size_t)0 * (B_ * S_),  &lB[BUF][tid * 8 + 0 * 2048]);            \
    gld_lds16(g_ + (size_t)32 * (B_ * S_), &lB[BUF][tid * 8 + 1 * 2048]);            \
    gld_lds16(g_ + (size_t)64 * (B_ * S_), &lB[BUF][tid * 8 + 2 * 2048]);            \
    gld_lds16(g_ + (size_t)96 * (B_ * S_), &lB[BUF][tid * 8 + 3 * 2048]);            \
  }

// One K-subtile. Order: bar1 / issue B(KK+1) EARLY / cvt pf(KK)->lA (compiler
// auto-waits vmcnt(4): retires A(KK)+B(KK), keeps B(KK+1)) / load A(KK+1) /
// counted vmcnt(12)=A(KK+1)+B(KK+1) + lgkm / bar2 / MFMA.
#define SUBITER(KK, RBUF, DOB, DOA, VM)                                              \
  {                                                                                  \
    __builtin_amdgcn_s_barrier();                                                    \
    __builtin_amdgcn_sched_barrier(0);                                               \
    if (DOB) ISSUE_B((RBUF) ^ 1, (KK) + 1);                                          \
    { /* cvt pf (tile KK) -> lA, swizzled chunk */                                   \
      u32x4 w_;                                                                      \
      w_[0] = cvtpk(pf0.x, pf0.y); w_[1] = cvtpk(pf0.z, pf0.w);                      \
      w_[2] = cvtpk(pf1.x, pf1.y); w_[3] = cvtpk(pf1.z, pf1.w);                      \
      *(u32x4*)(lA + 0 * 2048 + wrA) = w_;                                           \
      w_[0] = cvtpk(pf2.x, pf2.y); w_[1] = cvtpk(pf2.z, pf2.w);                      \
      w_[2] = cvtpk(pf3.x, pf3.y); w_[3] = cvtpk(pf3.z, pf3.w);                      \
      *(u32x4*)(lA + 1 * 2048 + wrA) = w_;                                           \
      w_[0] = cvtpk(pf4.x, pf4.y); w_[1] = cvtpk(pf4.z, pf4.w);                      \
      w_[2] = cvtpk(pf5.x, pf5.y); w_[3] = cvtpk(pf5.z, pf5.w);                      \
      *(u32x4*)(lA + 2 * 2048 + wrA) = w_;                                           \
      w_[0] = cvtpk(pf6.x, pf6.y); w_[1] = cvtpk(pf6.z, pf6.w);                      \
      w_[2] = cvtpk(pf7.x, pf7.y); w_[3] = cvtpk(pf7.z, pf7.w);                      \
      *(u32x4*)(lA + 3 * 2048 + wrA) = w_;                                           \
    }                                                                                \
    if (DOA) LOAD_PFA((KK) + 1);                                                     \
    asm volatile("s_waitcnt vmcnt(" #VM ") lgkmcnt(0)" ::: "memory");                \
    __builtin_amdgcn_sched_barrier(0);                                               \
    __builtin_amdgcn_s_barrier();                                                    \
    __builtin_amdgcn_sched_barrier(0);                                               \
    {                                                                                \
      const ushort_t* pA_ = lA + (wr * 64 + lr) * 64;                                \
      const ushort_t* pB_ = &lB[RBUF][(wc * 64 + lr) * 64];                          \
      __builtin_amdgcn_s_setprio(1);                                                 \
      _Pragma("unroll")                                                              \
      for (int ks = 0; ks < 2; ++ks) {                                               \
        const int co_ = ks ? cks1 : cks0;                                            \
        short8 av[4], bv[4];                                                         \
        _Pragma("unroll")                                                            \
        for (int mi = 0; mi < 4; ++mi) av[mi] = *(const short8*)(pA_ + mi * 1024 + co_);\
        _Pragma("unroll")                                                            \
        for (int ni = 0; ni < 4; ++ni) bv[ni] = *(const short8*)(pB_ + ni * 1024 + co_);\
        _Pragma("unroll")                                                            \
        for (int mi = 0; mi < 4; ++mi)                                               \
          _Pragma("unroll")                                                          \
          for (int ni = 0; ni < 4; ++ni)                                             \
            acc[mi][ni] = __builtin_amdgcn_mfma_f32_16x16x32_bf16(av[mi], bv[ni],    \
                                                                  acc[mi][ni], 0, 0, 0);\
      }                                                                              \
      __builtin_amdgcn_s_setprio(0);                                                 \
    }                                                                                \
  }

template <int SPLIT>
__global__ __launch_bounds__(256, 3) void k_gemm2f(const float* __restrict__ adj,
                                                   const ushort_t* __restrict__ hTg,
                                                   ushort_t* __restrict__ pdst,
                                                   float* __restrict__ fdst) {
  __shared__ __attribute__((aligned(16))) ushort_t lA[128 * 64];      // s x t
  __shared__ __attribute__((aligned(16))) ushort_t lB[2][128 * 64];   // o x t, dbuf
  const int tid = threadIdx.x;
  const int w = blockIdx.x;
  const int xcd = w & 7;
  const int r_ = w >> 3;
  const int xo = r_ & 3;          // o-tile
  const int yo = (r_ >> 2) & 3;   // s-tile
  const int zhi = r_ >> 4;        // z / 8
  const int z = xcd + 8 * zhi;    // 0..B_*SPLIT-1
  const int b = z / SPLIT, sp = z % SPLIT;
  const int o0 = xo * 128, s0 = yo * 128;
  constexpr int EPB = E_ / SPLIT;
  constexpr int NKK = EPB * 8;
  const int tr = tid >> 3;                      // staging row within 32-block
  const int tcf = (tid & 7) * 8;                // nominal col (elements)
  const int chS = (tid & 7) ^ (tr & 7);         // swizzled 16B chunk
  const int wrA = tr * 64 + chS * 8;            // lA write offset (elements)
  const int lane = tid & 63, wid = tid >> 6;
  const int wr = wid >> 1, wc = wid & 1;
  const int lr = lane & 15, lq = lane >> 4;
  const int rsw = lane & 7;                     // row&7 for fragment rows
  const int cks0 = (((lane >> 4) + 0) ^ rsw) * 8;
  const int cks1 = (((lane >> 4) + 4) ^ rsw) * 8;

  f32x4 acc[4][4];
#pragma unroll
  for (int i = 0; i < 4; ++i)
#pragma unroll
    for (int j = 0; j < 4; ++j) acc[i][j] = (f32x4){0.f, 0.f, 0.f, 0.f};

  float4 pf0, pf1, pf2, pf3, pf4, pf5, pf6, pf7;  // adj prefetch (compiler-tracked)

  // prologue: A(0) loads + B(0) gld_lds into buf 0
  LOAD_PFA(0);
  ISSUE_B(0, 0);

#pragma unroll 1
  for (int kk = 0; kk < NKK - 2; kk += 2) {
    SUBITER(kk, 0, 1, 1, 12)
    SUBITER(kk + 1, 1, 1, 1, 12)
  }
  SUBITER(NKK - 2, 0, 1, 1, 12)
  SUBITER(NKK - 1, 1, 0, 0, 0)

  if (SPLIT == 1) {
    float* base = fdst + (size_t)b * S_ * O_;
#pragma unroll
    for (int mi = 0; mi < 4; ++mi) {
      const int s_g = s0 + wr * 64 + mi * 16 + lq * 4;
#pragma unroll
      for (int ni = 0; ni < 4; ++ni) {
        const int o_g = o0 + wc * 64 + ni * 16 + lr;
        f32x4 v = acc[mi][ni];
#pragma unroll
        for (int r = 0; r < 4; ++r)
          base[(size_t)(s_g + r) * O_ + o_g] = fmaxf(v[r], 0.f);
      }
    }
  } else {
    ushort_t* base = pdst + ((size_t)sp * B_ + b) * S_ * O_;
#pragma unroll
    for (int mi = 0; mi < 4; ++mi) {
      const int s_g = s0 + wr * 64 + mi * 16 + lq * 4;
#pragma unroll
      for (int ni = 0; ni < 4; ++ni) {
        const int o_g = o0 + wc * 64 + ni * 16 + lr;
        f32x4 v = acc[mi][ni];
#pragma unroll
        for (int r = 0; r < 4; ++r)
          base[(size_t)(s_g + r) * O_ + o_g] = f2bf(v[r]);
      }
    }
  }
}

// reduce SPLIT bf16 partials + relu -> out (B,S,O) f32; 8 elems/thread
template <int SPLIT>
__global__ __launch_bounds__(256) void k_reduce(const ushort_t* __restrict__ part,
                                                float* __restrict__ out) {
  constexpr size_t N = (size_t)B_ * S_ * O_;
  size_t i8 = ((size_t)blockIdx.x * 256 + threadIdx.x) * 8;
  float a[8];
  ushort8 p0 = *(const ushort8*)(part + i8);
#pragma unroll
  for (int j = 0; j < 8; ++j) a[j] = bf2f(p0[j]);
#pragma unroll
  for (int s = 1; s < SPLIT; ++s) {
    ushort8 p = *(const ushort8*)(part + (size_t)s * N + i8);
#pragma unroll
    for (int j = 0; j < 8; ++j) a[j] += bf2f(p[j]);
  }
  f32x4 o0, o1;
  o0[0] = fmaxf(a[0], 0.f); o0[1] = fmaxf(a[1], 0.f);
  o0[2] = fmaxf(a[2], 0.f); o0[3] = fmaxf(a[3], 0.f);
  o1[0] = fmaxf(a[4], 0.f); o1[1] = fmaxf(a[5], 0.f);
  o1[2] = fmaxf(a[6], 0.f); o1[3] = fmaxf(a[7], 0.f);
  *(f32x4*)(out + i8) = o0;
  *(f32x4*)(out + i8 + 4) = o1;
}

// ---------------- launch ----------------

extern "C" void kernel_launch(void* const* d_in, const int* in_sizes, int n_in,
                              void* d_out, int out_size, void* d_ws, size_t ws_size,
                              hipStream_t stream) {
  const float* x   = (const float*)d_in[0];  // (B,S,D)
  const float* adj = (const float*)d_in[1];  // (B,E,S,S)
  const float* Wg  = (const float*)d_in[2];  // (E,D)
  const float* bg  = (const float*)d_in[3];  // (E,)
  const float* Wc  = (const float*)d_in[4];  // (E,D,O)
  const float* bc  = (const float*)d_in[5];  // (E,O)
  float* out = (float*)d_out;                // (B,S,O)

  // workspace carve (all 16B-aligned)
  char* ws = (char*)d_ws;
  float* gates  = (float*)ws;    ws += (size_t)B_ * E_ * S_ * 4;        //  0.26 MB
  ushort_t* xb  = (ushort_t*)ws; ws += (size_t)B_ * S_ * D_ * 2;        //  8.4  MB
  ushort_t* WcT = (ushort_t*)ws; ws += (size_t)E_ * O_ * D_ * 2;        //  4.2  MB
  ushort_t* hTg = (ushort_t*)ws; ws += (size_t)E_ * O_ * B_ * S_ * 2;   // 67.1  MB
  ushort_t* part = (ushort_t*)ws;                                       // SPLIT*8.4 MB
  const size_t base_bytes = (size_t)((char*)part - (char*)d_ws);
  const size_t part_sz = (size_t)B_ * S_ * O_ * sizeof(ushort_t);

  int split = 1;
  if (ws_size >= base_bytes + 4 * part_sz) split = 4;
  else if (ws_size >= base_bytes + 2 * part_sz) split = 2;

  k_prep<<<dim3((B_ * S_) / 4), dim3(256), 0, stream>>>(x, Wg, bg, gates, xb);
  k_wcT<<<dim3(O_ / 64, D_ / 64, E_), dim3(256), 0, stream>>>(Wc, WcT);
  k_gemm1g<<<dim3((E_ * O_) / 128, (B_ * S_) / 128), dim3(256), 0, stream>>>(WcT, xb, bc, gates, hTg);

  const int red_blocks = (int)(((size_t)B_ * S_ * O_) / (256 * 8));
  if (split == 4) {
    k_gemm2f<4><<<dim3(16 * B_ * 4), dim3(256), 0, stream>>>(adj, hTg, part, nullptr);
    k_reduce<4><<<dim3(red_blocks), dim3(256), 0, stream>>>(part, out);
  } else if (split == 2) {
    k_gemm2f<2><<<dim3(16 * B_ * 2), dim3(256), 0, stream>>>(adj, hTg, part, nullptr);
    k_reduce<2><<<dim3(red_blocks), dim3(256), 0, stream>>>(part, out);
  } else {
    k_gemm2f<1><<<dim3(16 * B_), dim3(256), 0, stream>>>(adj, hTg, nullptr, out);
  }
}